// Round 1
// baseline (1701.174 us; speedup 1.0000x reference)
//
#include <hip/hip_runtime.h>
#include <math.h>

#define B_ 2
#define C_ 256
#define N_ 4096
#define TXT_ 512
#define CH_ 128
#define TN 32
#define GT 64
#define GK 32

typedef unsigned short u16;

__device__ __forceinline__ float bf2f(u16 v){
  union { unsigned u; float f; } w; w.u = ((unsigned)v) << 16; return w.f;
}
__device__ __forceinline__ u16 f2bf(float f){
  union { float f; unsigned u; } w; w.f = f;
  unsigned r = w.u + 0x7fffu + ((w.u >> 16) & 1u);
  return (u16)(r >> 16);
}

// ---------- text pipeline: txt_emb, attn constant (v@wo^T+bo), txt_n ----------
__global__ __launch_bounds__(256) void k_text(
    const float* __restrict__ txt, const float* __restrict__ tpw,
    const float* __restrict__ tpb, const float* __restrict__ wv,
    const float* __restrict__ bv, const float* __restrict__ wo,
    const float* __restrict__ bo,
    float* __restrict__ txt_emb, float* __restrict__ attn_c, float* __restrict__ txt_n)
{
  int b = blockIdx.x, t = threadIdx.x;
  __shared__ float te[C_], vs[C_], red[C_];
  const float* tb = txt + b * TXT_;
  const float* wr = tpw + (size_t)t * TXT_;
  float s = 0.f;
  for (int j = 0; j < TXT_; j++) s += tb[j] * wr[j];
  s += tpb[t];
  te[t] = s;
  txt_emb[b * C_ + t] = s;
  __syncthreads();
  float sv = 0.f;
  const float* wvr = wv + (size_t)t * C_;
  for (int j = 0; j < C_; j++) sv += te[j] * wvr[j];
  sv += bv[t];
  vs[t] = sv;
  __syncthreads();
  float sa = 0.f;
  const float* wor = wo + (size_t)t * C_;
  for (int j = 0; j < C_; j++) sa += vs[j] * wor[j];
  sa += bo[t];
  attn_c[b * C_ + t] = sa;
  red[t] = te[t] * te[t];
  __syncthreads();
  for (int o = 128; o > 0; o >>= 1){ if (t < o) red[t] += red[t + o]; __syncthreads(); }
  float nrm = sqrtf(red[0]);
  float inv = 1.f / fmaxf(nrm, 1e-12f);
  txt_n[b * C_ + t] = te[t] * inv;
}

// ---------- source (residual+LN), sn (l2norm over C), cos ----------
__global__ __launch_bounds__(256) void k_source(
    const float* __restrict__ img, const float* __restrict__ attn_c,
    const float* __restrict__ ln_g, const float* __restrict__ ln_b,
    const float* __restrict__ txt_n,
    float* __restrict__ source, float* __restrict__ snb, float* __restrict__ cosv)
{
  int b = blockIdx.y;
  int n0 = blockIdx.x * TN;
  int t = threadIdx.x;
  __shared__ float x[C_][TN + 1];
  __shared__ float ps[8][TN];
  __shared__ float ps2[8][TN];
  __shared__ float ac_s[C_], g_s[C_], bb_s[C_], tn_s[C_];
  __shared__ float mean_s[TN], rstd_s[TN], rn_s[TN];
  ac_s[t] = attn_c[b * C_ + t];
  g_s[t]  = ln_g[t];
  bb_s[t] = ln_b[t];
  tn_s[t] = txt_n[b * C_ + t];
  const float* ib = img + (size_t)b * C_ * N_ + n0;
  for (int k = 0; k < TN; k++){
    int e = t + k * 256;
    int c = e >> 5, nn = e & 31;
    x[c][nn] = ib[(size_t)c * N_ + nn];
  }
  __syncthreads();
  for (int k = 0; k < TN; k++){
    int e = t + k * 256;
    int c = e >> 5, nn = e & 31;
    x[c][nn] += ac_s[c];
  }
  __syncthreads();
  {
    int p = t >> 5, nn = t & 31;
    float s1 = 0.f, s2 = 0.f;
    for (int j = 0; j < 32; j++){
      float v = x[p + 8 * j][nn];
      s1 += v; s2 += v * v;
    }
    ps[p][nn] = s1; ps2[p][nn] = s2;
  }
  __syncthreads();
  if (t < TN){
    float S1 = 0.f, S2 = 0.f;
    for (int pp = 0; pp < 8; pp++){ S1 += ps[pp][t]; S2 += ps2[pp][t]; }
    float mean = S1 * (1.f / C_);
    float var = S2 * (1.f / C_) - mean * mean;
    mean_s[t] = mean;
    rstd_s[t] = rsqrtf(var + 1e-5f);
  }
  __syncthreads();
  // per thread: channel c = t, position nn = k
  for (int k = 0; k < TN; k++){
    float sval = (x[t][k] - mean_s[k]) * rstd_s[k] * g_s[t] + bb_s[t];
    source[(size_t)((b << 12) + n0 + k) * C_ + t] = sval;
    x[t][k] = sval;
  }
  __syncthreads();
  {
    int p = t >> 5, nn = t & 31;
    float s2 = 0.f, sd = 0.f;
    for (int j = 0; j < 32; j++){
      int c = p + 8 * j;
      float v = x[c][nn];
      s2 += v * v; sd += v * tn_s[c];
    }
    ps[p][nn] = s2; ps2[p][nn] = sd;
  }
  __syncthreads();
  if (t < TN){
    float S2 = 0.f, SD = 0.f;
    for (int pp = 0; pp < 8; pp++){ S2 += ps[pp][t]; SD += ps2[pp][t]; }
    float nrm = sqrtf(S2);
    float rn = 1.f / fmaxf(nrm, 1e-12f);
    rn_s[t] = rn;
    cosv[(b << 12) + n0 + t] = SD * rn;
  }
  __syncthreads();
  for (int k = 0; k < TN; k++){
    snb[(size_t)((b << 12) + n0 + k) * C_ + t] = x[t][k] * rn_s[k];
  }
}

// ---------- marginals ----------
__global__ __launch_bounds__(256) void k_qmarg(const float* __restrict__ dens, float* __restrict__ q){
  int b = blockIdx.x, t = threadIdx.x;
  __shared__ float red[256];
  const float* d = dens + (size_t)b * N_;
  float s = 0.f;
  for (int n = t; n < N_; n += 256) s += fmaxf(d[n], 0.f) + 1e-6f;
  red[t] = s; __syncthreads();
  for (int o = 128; o > 0; o >>= 1){ if (t < o) red[t] += red[t + o]; __syncthreads(); }
  float inv = 1.f / red[0];
  for (int n = t; n < N_; n += 256) q[b * N_ + n] = (fmaxf(d[n], 0.f) + 1e-6f) * inv;
}

__global__ __launch_bounds__(256) void k_pmarg(const float* __restrict__ cosv,
    const float* __restrict__ temp_p, float* __restrict__ p){
  int b = blockIdx.x, t = threadIdx.x;
  __shared__ float red[256];
  float temp = fmaxf(temp_p[0], 0.01f);
  float inv_t = 1.f / temp;
  const float* cb = cosv + (size_t)b * N_;
  float m = -1e30f;
  for (int n = t; n < N_; n += 256) m = fmaxf(m, cb[n] * inv_t);
  red[t] = m; __syncthreads();
  for (int o = 128; o > 0; o >>= 1){ if (t < o) red[t] = fmaxf(red[t], red[t + o]); __syncthreads(); }
  m = red[0]; __syncthreads();
  float s = 0.f;
  for (int n = t; n < N_; n += 256) s += expf(cb[n] * inv_t - m);
  red[t] = s; __syncthreads();
  for (int o = 128; o > 0; o >>= 1){ if (t < o) red[t] += red[t + o]; __syncthreads(); }
  float invs = 1.f / red[0];
  for (int n = t; n < N_; n += 256) p[b * N_ + n] = expf(cb[n] * inv_t - m) * invs;
}

__global__ __launch_bounds__(256) void k_zero(float* __restrict__ p, int n){
  int i = blockIdx.x * 256 + threadIdx.x;
  if (i < n) p[i] = 0.f;
}

// ---------- K = exp(20*(sn sn^T - 1)) (bf16) + column sums ----------
__global__ __launch_bounds__(256) void k_kgen(
    const float* __restrict__ snb, u16* __restrict__ K, float* __restrict__ colsum)
{
  int b = blockIdx.z;
  int m0 = blockIdx.x * GT;
  int n0 = blockIdx.y * GT;
  int t = threadIdx.x;
  int tx = t & 15, ty = t >> 4;
  __shared__ __align__(16) float As[GK][68];
  __shared__ __align__(16) float Bs[GK][68];
  __shared__ float cs[GT];
  if (t < GT) cs[t] = 0.f;
  float acc[4][4] = {};
  const float* sb = snb + (size_t)b * N_ * C_;
  for (int c0 = 0; c0 < C_; c0 += GK){
    for (int e = t; e < GT * GK; e += 256){
      int r = e >> 5, kk = e & 31;
      As[kk][r] = sb[(size_t)(n0 + r) * C_ + c0 + kk];
      Bs[kk][r] = sb[(size_t)(m0 + r) * C_ + c0 + kk];
    }
    __syncthreads();
    #pragma unroll
    for (int kk = 0; kk < GK; kk++){
      float4 a4 = *reinterpret_cast<const float4*>(&As[kk][ty * 4]);
      float4 b4 = *reinterpret_cast<const float4*>(&Bs[kk][tx * 4]);
      float ar[4] = {a4.x, a4.y, a4.z, a4.w};
      float br[4] = {b4.x, b4.y, b4.z, b4.w};
      #pragma unroll
      for (int i = 0; i < 4; i++)
        #pragma unroll
        for (int j = 0; j < 4; j++)
          acc[i][j] += ar[i] * br[j];
    }
    __syncthreads();
  }
  u16* Kb = K + (size_t)b * N_ * N_;
  float cp[4] = {0.f, 0.f, 0.f, 0.f};
  for (int i = 0; i < 4; i++){
    int n = n0 + ty * 4 + i;
    ushort4 pk;
    pk.x = f2bf(expf(20.f * (acc[i][0] - 1.f)));
    pk.y = f2bf(expf(20.f * (acc[i][1] - 1.f)));
    pk.z = f2bf(expf(20.f * (acc[i][2] - 1.f)));
    pk.w = f2bf(expf(20.f * (acc[i][3] - 1.f)));
    cp[0] += bf2f(pk.x); cp[1] += bf2f(pk.y); cp[2] += bf2f(pk.z); cp[3] += bf2f(pk.w);
    *reinterpret_cast<ushort4*>(&Kb[(size_t)n * N_ + m0 + tx * 4]) = pk;
  }
  for (int j = 0; j < 4; j++) atomicAdd(&cs[tx * 4 + j], cp[j]);
  __syncthreads();
  if (t < GT) atomicAdd(&colsum[b * N_ + m0 + t], cs[t]);
}

__global__ __launch_bounds__(256) void k_div(
    const float* __restrict__ marg, const float* __restrict__ denom, float* __restrict__ outp){
  int i = blockIdx.x * 256 + threadIdx.x;
  if (i < B_ * N_) outp[i] = marg[i] / (denom[i] + 1e-8f);
}

// ---------- tmp[m] += sum_n K[n][m] * x[n]   (K^T x) ----------
__global__ __launch_bounds__(256) void k_ktx(
    const u16* __restrict__ K, const float* __restrict__ xin, float* __restrict__ tmp)
{
  int b = blockIdx.y;
  int n0 = blockIdx.x * 64;
  int t = threadIdx.x;
  __shared__ float xs[64];
  if (t < 64) xs[t] = xin[b * N_ + n0 + t];
  __syncthreads();
  const u16* Kb = K + (size_t)b * N_ * N_ + (size_t)n0 * N_;
  for (int m = t; m < N_; m += 256){
    float acc = 0.f;
    #pragma unroll 8
    for (int i = 0; i < 64; i++) acc += bf2f(Kb[(size_t)i * N_ + m]) * xs[i];
    atomicAdd(&tmp[b * N_ + m], acc);
  }
}

// ---------- u[n] = p[n] / (sum_m K[n][m] * vv[m] + 1e-8) ----------
__global__ __launch_bounds__(256) void k_kx(
    const u16* __restrict__ K, const float* __restrict__ vvv,
    const float* __restrict__ marg, float* __restrict__ uo)
{
  int t = threadIdx.x;
  int w = t >> 6, lane = t & 63;
  int r = blockIdx.x * 4 + w;
  int b = r >> 12, n = r & (N_ - 1);
  const u16* Kr = K + (size_t)b * N_ * N_ + (size_t)n * N_;
  const float* vb = vvv + b * N_;
  float acc = 0.f;
  for (int m = lane; m < N_; m += 64) acc += bf2f(Kr[m]) * vb[m];
  for (int o = 32; o > 0; o >>= 1) acc += __shfl_down(acc, o);
  if (lane == 0) uo[r] = marg[r] / (acc + 1e-8f);
}

// ---------- fused[m][c] = vv[m] * sum_n K[n][m] * u[n] * source[n][c] ----------
__global__ __launch_bounds__(256) void k_full(
    const u16* __restrict__ K, const float* __restrict__ source,
    const float* __restrict__ uu, const float* __restrict__ vvv,
    float* __restrict__ fused)
{
  int b = blockIdx.z;
  int m0 = blockIdx.x * GT;
  int c0 = blockIdx.y * GT;
  int t = threadIdx.x, tx = t & 15, ty = t >> 4;
  __shared__ __align__(16) float Ks[GK][68];
  __shared__ __align__(16) float Ss[GK][68];
  float acc[4][4] = {};
  const u16* Kb = K + (size_t)b * N_ * N_;
  const float* sb = source + (size_t)b * N_ * C_;
  const float* ub = uu + b * N_;
  for (int n0 = 0; n0 < N_; n0 += GK){
    for (int e = t; e < GK * GT; e += 256){
      int row = e >> 6, mm = e & 63;
      Ks[row][mm] = bf2f(Kb[(size_t)(n0 + row) * N_ + m0 + mm]);
      Ss[row][mm] = sb[(size_t)(n0 + row) * C_ + c0 + mm] * ub[n0 + row];
    }
    __syncthreads();
    #pragma unroll
    for (int kk = 0; kk < GK; kk++){
      float4 a4 = *reinterpret_cast<const float4*>(&Ks[kk][ty * 4]);
      float4 b4 = *reinterpret_cast<const float4*>(&Ss[kk][tx * 4]);
      float ar[4] = {a4.x, a4.y, a4.z, a4.w};
      float br[4] = {b4.x, b4.y, b4.z, b4.w};
      #pragma unroll
      for (int i = 0; i < 4; i++)
        #pragma unroll
        for (int j = 0; j < 4; j++)
          acc[i][j] += ar[i] * br[j];
    }
    __syncthreads();
  }
  for (int i = 0; i < 4; i++){
    int m = m0 + ty * 4 + i;
    float vvm = vvv[b * N_ + m];
    float4 o;
    o.x = acc[i][0] * vvm; o.y = acc[i][1] * vvm;
    o.z = acc[i][2] * vvm; o.w = acc[i][3] * vvm;
    *reinterpret_cast<float4*>(&fused[(size_t)((b << 12) + m) * C_ + c0 + tx * 4]) = o;
  }
}

// ---------- out_feat = img + 1x1conv(fused) ----------
__global__ __launch_bounds__(256) void k_opconv(
    const float* __restrict__ opw, const float* __restrict__ opb,
    const float* __restrict__ fused, const float* __restrict__ img,
    float* __restrict__ outf)
{
  int b = blockIdx.z;
  int n0 = blockIdx.x * GT;
  int co0 = blockIdx.y * GT;
  int t = threadIdx.x, tx = t & 15, ty = t >> 4;
  __shared__ __align__(16) float Ws[GK][68];
  __shared__ __align__(16) float Fs[GK][68];
  float acc[4][4] = {};
  for (int c0 = 0; c0 < C_; c0 += GK){
    for (int e = t; e < GT * GK; e += 256){
      int a_ = e >> 5, i_ = e & 31;
      Ws[i_][a_] = opw[(size_t)(co0 + a_) * C_ + c0 + i_];
      Fs[i_][a_] = fused[(size_t)((b << 12) + n0 + a_) * C_ + c0 + i_];
    }
    __syncthreads();
    #pragma unroll
    for (int kk = 0; kk < GK; kk++){
      float4 a4 = *reinterpret_cast<const float4*>(&Ws[kk][ty * 4]);
      float4 b4 = *reinterpret_cast<const float4*>(&Fs[kk][tx * 4]);
      float ar[4] = {a4.x, a4.y, a4.z, a4.w};
      float br[4] = {b4.x, b4.y, b4.z, b4.w};
      #pragma unroll
      for (int i = 0; i < 4; i++)
        #pragma unroll
        for (int j = 0; j < 4; j++)
          acc[i][j] += ar[i] * br[j];
    }
    __syncthreads();
  }
  for (int i = 0; i < 4; i++){
    int co = co0 + ty * 4 + i;
    const float4 iv = *reinterpret_cast<const float4*>(&img[(size_t)(b * C_ + co) * N_ + n0 + tx * 4]);
    float ob = opb[co];
    float4 o;
    o.x = iv.x + acc[i][0] + ob; o.y = iv.y + acc[i][1] + ob;
    o.z = iv.z + acc[i][2] + ob; o.w = iv.w + acc[i][3] + ob;
    *reinterpret_cast<float4*>(&outf[(size_t)(b * C_ + co) * N_ + n0 + tx * 4]) = o;
  }
}

// ---------- 3x3 conv 256->128, pad 1 ----------
__global__ __launch_bounds__(256) void k_conv3(
    const float* __restrict__ inf, const float* __restrict__ w,
    const float* __restrict__ bias, float* __restrict__ mid)
{
  int b = blockIdx.z;
  int y = blockIdx.x;         // 0..63
  int co0 = blockIdx.y * 64;  // 0 or 64
  int t = threadIdx.x, tx = t & 15, ty = t >> 4;
  __shared__ float in_s[8][3][68];
  __shared__ float w_s[64][73];
  float acc[4][4] = {};
  for (int c0 = 0; c0 < C_; c0 += 8){
    for (int e = t; e < 8 * 3 * 66; e += 256){
      int ci = e / 198, rem = e % 198, ry = rem / 66, xx = rem % 66;
      int yy = y + ry - 1, xg = xx - 1;
      float v = 0.f;
      if (yy >= 0 && yy < 64 && xg >= 0 && xg < 64)
        v = inf[(size_t)(b * C_ + c0 + ci) * N_ + yy * 64 + xg];
      in_s[ci][ry][xx] = v;
    }
    for (int e = t; e < 64 * 72; e += 256){
      int co = e / 72, r = e % 72;
      w_s[co][r] = w[(size_t)(co0 + co) * C_ * 9 + c0 * 9 + r];
    }
    __syncthreads();
    for (int ci = 0; ci < 8; ci++){
      #pragma unroll
      for (int ky = 0; ky < 3; ky++){
        float iv[6];
        #pragma unroll
        for (int q = 0; q < 6; q++) iv[q] = in_s[ci][ky][tx * 4 + q];
        #pragma unroll
        for (int kx = 0; kx < 3; kx++){
          #pragma unroll
          for (int i = 0; i < 4; i++){
            float wv = w_s[ty * 4 + i][ci * 9 + ky * 3 + kx];
            #pragma unroll
            for (int j = 0; j < 4; j++) acc[i][j] += wv * iv[j + kx];
          }
        }
      }
    }
    __syncthreads();
  }
  for (int i = 0; i < 4; i++){
    int co = co0 + ty * 4 + i;
    float bv = bias[co];
    float4 o = {acc[i][0] + bv, acc[i][1] + bv, acc[i][2] + bv, acc[i][3] + bv};
    *reinterpret_cast<float4*>(&mid[(size_t)(b * CH_ + co) * N_ + y * 64 + tx * 4]) = o;
  }
}

// ---------- batchnorm stats over (B,H,W) per channel ----------
__global__ __launch_bounds__(256) void k_bnstats(const float* __restrict__ mid, float* __restrict__ stats){
  int ch = blockIdx.x, t = threadIdx.x;
  __shared__ float r1[256], r2[256];
  float s1 = 0.f, s2 = 0.f;
  for (int i = t; i < B_ * N_; i += 256){
    int b = i >> 12, n = i & (N_ - 1);
    float v = mid[(size_t)(b * CH_ + ch) * N_ + n];
    s1 += v; s2 += v * v;
  }
  r1[t] = s1; r2[t] = s2; __syncthreads();
  for (int o = 128; o > 0; o >>= 1){
    if (t < o){ r1[t] += r1[t + o]; r2[t] += r2[t + o]; }
    __syncthreads();
  }
  if (t == 0){
    float mean = r1[0] / (float)(B_ * N_);
    float var = r2[0] / (float)(B_ * N_) - mean * mean;
    stats[ch * 2] = mean;
    stats[ch * 2 + 1] = rsqrtf(var + 1e-5f);
  }
}

// ---------- relu(bn(mid)) -> 1x1 conv to 2 channels ----------
__global__ __launch_bounds__(256) void k_head(
    const float* __restrict__ mid, const float* __restrict__ stats,
    const float* __restrict__ g, const float* __restrict__ bb,
    const float* __restrict__ w2, const float* __restrict__ b2,
    float* __restrict__ outp)
{
  int idx = blockIdx.x * 256 + threadIdx.x;
  int b = idx >> 12, n = idx & (N_ - 1);
  float a0 = 0.f, a1 = 0.f;
  for (int ch = 0; ch < CH_; ch++){
    float v = mid[(size_t)(b * CH_ + ch) * N_ + n];
    float rr = (v - stats[ch * 2]) * stats[ch * 2 + 1] * g[ch] + bb[ch];
    rr = fmaxf(rr, 0.f);
    a0 += w2[ch] * rr;
    a1 += w2[CH_ + ch] * rr;
  }
  outp[(size_t)(b * 2) * N_ + n] = a0 + b2[0];
  outp[(size_t)(b * 2 + 1) * N_ + n] = a1 + b2[1];
}

extern "C" void kernel_launch(void* const* d_in, const int* in_sizes, int n_in,
                              void* d_out, int out_size, void* d_ws, size_t ws_size,
                              hipStream_t stream)
{
  const float* img   = (const float*)d_in[0];
  const float* txt   = (const float*)d_in[1];
  const float* dens  = (const float*)d_in[2];
  const float* tp_w  = (const float*)d_in[3];
  const float* tp_b  = (const float*)d_in[4];
  const float* wv    = (const float*)d_in[9];
  const float* bv    = (const float*)d_in[10];
  const float* wo    = (const float*)d_in[11];
  const float* bo    = (const float*)d_in[12];
  const float* ln_g  = (const float*)d_in[13];
  const float* ln_b  = (const float*)d_in[14];
  const float* op_w  = (const float*)d_in[15];
  const float* op_b  = (const float*)d_in[16];
  const float* hm1_w = (const float*)d_in[17];
  const float* hm1_b = (const float*)d_in[18];
  const float* hm_g  = (const float*)d_in[19];
  const float* hm_b  = (const float*)d_in[20];
  const float* hm2_w = (const float*)d_in[21];
  const float* hm2_b = (const float*)d_in[22];
  const float* hv1_w = (const float*)d_in[23];
  const float* hv1_b = (const float*)d_in[24];
  const float* hv_g  = (const float*)d_in[25];
  const float* hv_b  = (const float*)d_in[26];
  const float* hv2_w = (const float*)d_in[27];
  const float* hv2_b = (const float*)d_in[28];
  const float* temp  = (const float*)d_in[29];

  char* wsb = (char*)d_ws;
  size_t off = 0;
  auto alloc = [&](size_t bytes) -> void* {
    void* p = wsb + off;
    off += (bytes + 255) & ~(size_t)255;
    return p;
  };
  u16*   Km     = (u16*)  alloc((size_t)B_ * N_ * N_ * sizeof(u16));
  float* source = (float*)alloc((size_t)B_ * N_ * C_ * sizeof(float));
  float* snb    = (float*)alloc((size_t)B_ * N_ * C_ * sizeof(float));
  float* fused  = (float*)alloc((size_t)B_ * N_ * C_ * sizeof(float));
  float* mid    = (float*)alloc((size_t)B_ * CH_ * N_ * sizeof(float));
  float* txt_emb= (float*)alloc(B_ * C_ * sizeof(float));
  float* attn_c = (float*)alloc(B_ * C_ * sizeof(float));
  float* txt_n  = (float*)alloc(B_ * C_ * sizeof(float));
  float* cosv   = (float*)alloc(B_ * N_ * sizeof(float));
  float* qm     = (float*)alloc(B_ * N_ * sizeof(float));
  float* pm     = (float*)alloc(B_ * N_ * sizeof(float));
  float* uu     = (float*)alloc(B_ * N_ * sizeof(float));
  float* vvv    = (float*)alloc(B_ * N_ * sizeof(float));
  float* tmp    = (float*)alloc(B_ * N_ * sizeof(float));
  float* colsum = (float*)alloc(B_ * N_ * sizeof(float));
  float* stats  = (float*)alloc(CH_ * 2 * sizeof(float));

  float* outf  = (float*)d_out;
  float* outhm = outf + (size_t)B_ * C_ * N_;
  float* outhv = outhm + (size_t)B_ * 2 * N_;

  k_text<<<B_, 256, 0, stream>>>(txt, tp_w, tp_b, wv, bv, wo, bo, txt_emb, attn_c, txt_n);
  k_source<<<dim3(N_ / TN, B_), 256, 0, stream>>>(img, attn_c, ln_g, ln_b, txt_n, source, snb, cosv);
  k_qmarg<<<B_, 256, 0, stream>>>(dens, qm);
  k_pmarg<<<B_, 256, 0, stream>>>(cosv, temp, pm);
  k_zero<<<(B_ * N_ + 255) / 256, 256, 0, stream>>>(colsum, B_ * N_);
  k_kgen<<<dim3(N_ / GT, N_ / GT, B_), 256, 0, stream>>>(snb, Km, colsum);
  // Sinkhorn: vv1 from colsum (u0 = ones), then alternate
  k_div<<<(B_ * N_ + 255) / 256, 256, 0, stream>>>(qm, colsum, vvv);
  k_kx<<<B_ * N_ / 4, 256, 0, stream>>>(Km, vvv, pm, uu);
  for (int it = 0; it < 2; ++it){
    k_zero<<<(B_ * N_ + 255) / 256, 256, 0, stream>>>(tmp, B_ * N_);
    k_ktx<<<dim3(N_ / 64, B_), 256, 0, stream>>>(Km, uu, tmp);
    k_div<<<(B_ * N_ + 255) / 256, 256, 0, stream>>>(qm, tmp, vvv);
    k_kx<<<B_ * N_ / 4, 256, 0, stream>>>(Km, vvv, pm, uu);
  }
  k_full<<<dim3(N_ / GT, C_ / GT, B_), 256, 0, stream>>>(Km, source, uu, vvv, fused);
  k_opconv<<<dim3(N_ / GT, C_ / GT, B_), 256, 0, stream>>>(op_w, op_b, fused, img, outf);
  // hm head
  k_conv3<<<dim3(64, 2, B_), 256, 0, stream>>>(outf, hm1_w, hm1_b, mid);
  k_bnstats<<<CH_, 256, 0, stream>>>(mid, stats);
  k_head<<<B_ * N_ / 256, 256, 0, stream>>>(mid, stats, hm_g, hm_b, hm2_w, hm2_b, outhm);
  // hv head
  k_conv3<<<dim3(64, 2, B_), 256, 0, stream>>>(outf, hv1_w, hv1_b, mid);
  k_bnstats<<<CH_, 256, 0, stream>>>(mid, stats);
  k_head<<<B_ * N_ / 256, 256, 0, stream>>>(mid, stats, hv_g, hv_b, hv2_w, hv2_b, outhv);
}

// Round 2
// 731.859 us; speedup vs baseline: 2.3245x; 2.3245x over previous
//
#include <hip/hip_runtime.h>
#include <math.h>

#define B_ 2
#define C_ 256
#define N_ 4096
#define TXT_ 512
#define CH_ 128
#define TN 32
#define GT 64
#define GK 32
#define KSPLIT 2

typedef unsigned short u16;
typedef __attribute__((ext_vector_type(8))) short short8;
typedef __attribute__((ext_vector_type(4))) float f32x4;

__device__ __forceinline__ float bf2f(u16 v){
  union { unsigned u; float f; } w; w.u = ((unsigned)v) << 16; return w.f;
}
__device__ __forceinline__ u16 f2bf(float f){
  union { float f; unsigned u; } w; w.f = f;
  unsigned r = w.u + 0x7fffu + ((w.u >> 16) & 1u);
  return (u16)(r >> 16);
}

#define MFMA_BF16(a,b,c) __builtin_amdgcn_mfma_f32_16x16x32_bf16(a,b,c,0,0,0)

// Stage a 128-row x 64-col bf16 tile from global (row stride `stride` elems) into
// LDS via global_load_lds (linear dest). Source addresses are pre-swizzled so the
// LDS holds the XOR-swizzled tile; frag_ld applies the same XOR on read (m173/m201).
__device__ __forceinline__ void stage_tile(const u16* __restrict__ g, int stride, u16* lds, int t)
{
  #pragma unroll
  for (int q = 0; q < 4; q++){
    int e = q * 256 + t;          // 16B unit index
    int row = e >> 3;             // 8 units per 128B row
    int slot = e & 7;
    const u16* gp = g + (size_t)row * stride + ((slot ^ (row & 7)) << 3);
    u16* lp = lds + (size_t)e * 8;
    __builtin_amdgcn_global_load_lds((const __attribute__((address_space(1))) void*)gp,
                                     (__attribute__((address_space(3))) void*)lp, 16, 0, 0);
  }
}

__device__ __forceinline__ short8 frag_ld(const u16* lds, int row, int slot)
{
  return *(const short8*)(lds + row * 64 + ((slot ^ (row & 7)) << 3));
}

// ---------- text pipeline: txt_emb, attn constant (v@wo^T+bo), txt_n ----------
__global__ __launch_bounds__(256) void k_text(
    const float* __restrict__ txt, const float* __restrict__ tpw,
    const float* __restrict__ tpb, const float* __restrict__ wv,
    const float* __restrict__ bv, const float* __restrict__ wo,
    const float* __restrict__ bo,
    float* __restrict__ txt_emb, float* __restrict__ attn_c, float* __restrict__ txt_n)
{
  int b = blockIdx.x, t = threadIdx.x;
  __shared__ float te[C_], vs[C_], red[C_];
  const float* tb = txt + b * TXT_;
  const float* wr = tpw + (size_t)t * TXT_;
  float s = 0.f;
  for (int j = 0; j < TXT_; j++) s += tb[j] * wr[j];
  s += tpb[t];
  te[t] = s;
  txt_emb[b * C_ + t] = s;
  __syncthreads();
  float sv = 0.f;
  const float* wvr = wv + (size_t)t * C_;
  for (int j = 0; j < C_; j++) sv += te[j] * wvr[j];
  sv += bv[t];
  vs[t] = sv;
  __syncthreads();
  float sa = 0.f;
  const float* wor = wo + (size_t)t * C_;
  for (int j = 0; j < C_; j++) sa += vs[j] * wor[j];
  sa += bo[t];
  attn_c[b * C_ + t] = sa;
  red[t] = te[t] * te[t];
  __syncthreads();
  for (int o = 128; o > 0; o >>= 1){ if (t < o) red[t] += red[t + o]; __syncthreads(); }
  float nrm = sqrtf(red[0]);
  float inv = 1.f / fmaxf(nrm, 1e-12f);
  txt_n[b * C_ + t] = te[t] * inv;
}

// ---------- source (residual+LN) -> srcT bf16 [C][N], snb bf16 [N][C], cos ----------
__global__ __launch_bounds__(256) void k_source(
    const float* __restrict__ img, const float* __restrict__ attn_c,
    const float* __restrict__ ln_g, const float* __restrict__ ln_b,
    const float* __restrict__ txt_n,
    u16* __restrict__ srcT, u16* __restrict__ snb, float* __restrict__ cosv)
{
  int b = blockIdx.y;
  int n0 = blockIdx.x * TN;
  int t = threadIdx.x;
  __shared__ float x[C_][TN + 1];
  __shared__ float ps[8][TN];
  __shared__ float ps2[8][TN];
  __shared__ float ac_s[C_], g_s[C_], bb_s[C_], tn_s[C_];
  __shared__ float mean_s[TN], rstd_s[TN], rn_s[TN];
  ac_s[t] = attn_c[b * C_ + t];
  g_s[t]  = ln_g[t];
  bb_s[t] = ln_b[t];
  tn_s[t] = txt_n[b * C_ + t];
  const float* ib = img + (size_t)b * C_ * N_ + n0;
  for (int k = 0; k < TN; k++){
    int e = t + k * 256;
    int c = e >> 5, nn = e & 31;
    x[c][nn] = ib[(size_t)c * N_ + nn];
  }
  __syncthreads();
  for (int k = 0; k < TN; k++){
    int e = t + k * 256;
    int c = e >> 5, nn = e & 31;
    x[c][nn] += ac_s[c];
  }
  __syncthreads();
  {
    int p = t >> 5, nn = t & 31;
    float s1 = 0.f, s2 = 0.f;
    for (int j = 0; j < 32; j++){
      float v = x[p + 8 * j][nn];
      s1 += v; s2 += v * v;
    }
    ps[p][nn] = s1; ps2[p][nn] = s2;
  }
  __syncthreads();
  if (t < TN){
    float S1 = 0.f, S2 = 0.f;
    for (int pp = 0; pp < 8; pp++){ S1 += ps[pp][t]; S2 += ps2[pp][t]; }
    float mean = S1 * (1.f / C_);
    float var = S2 * (1.f / C_) - mean * mean;
    mean_s[t] = mean;
    rstd_s[t] = rsqrtf(var + 1e-5f);
  }
  __syncthreads();
  // per thread: channel c = t, position nn = k
  for (int k = 0; k < TN; k++){
    float sval = (x[t][k] - mean_s[k]) * rstd_s[k] * g_s[t] + bb_s[t];
    x[t][k] = sval;
  }
  // srcT [b][c=t][n] bf16, packed 8B stores
  for (int kq = 0; kq < TN; kq += 4){
    ushort4 pkv;
    pkv.x = f2bf(x[t][kq + 0]);
    pkv.y = f2bf(x[t][kq + 1]);
    pkv.z = f2bf(x[t][kq + 2]);
    pkv.w = f2bf(x[t][kq + 3]);
    *reinterpret_cast<ushort4*>(&srcT[(size_t)(b * C_ + t) * N_ + n0 + kq]) = pkv;
  }
  __syncthreads();
  {
    int p = t >> 5, nn = t & 31;
    float s2 = 0.f, sd = 0.f;
    for (int j = 0; j < 32; j++){
      int c = p + 8 * j;
      float v = x[c][nn];
      s2 += v * v; sd += v * tn_s[c];
    }
    ps[p][nn] = s2; ps2[p][nn] = sd;
  }
  __syncthreads();
  if (t < TN){
    float S2 = 0.f, SD = 0.f;
    for (int pp = 0; pp < 8; pp++){ S2 += ps[pp][t]; SD += ps2[pp][t]; }
    float nrm = sqrtf(S2);
    float rn = 1.f / fmaxf(nrm, 1e-12f);
    rn_s[t] = rn;
    cosv[(b << 12) + n0 + t] = SD * rn;
  }
  __syncthreads();
  for (int k = 0; k < TN; k++){
    snb[(size_t)((b << 12) + n0 + k) * C_ + t] = f2bf(x[t][k] * rn_s[k]);
  }
}

// ---------- marginals ----------
__global__ __launch_bounds__(256) void k_qmarg(const float* __restrict__ dens, float* __restrict__ q){
  int b = blockIdx.x, t = threadIdx.x;
  __shared__ float red[256];
  const float* d = dens + (size_t)b * N_;
  float s = 0.f;
  for (int n = t; n < N_; n += 256) s += fmaxf(d[n], 0.f) + 1e-6f;
  red[t] = s; __syncthreads();
  for (int o = 128; o > 0; o >>= 1){ if (t < o) red[t] += red[t + o]; __syncthreads(); }
  float inv = 1.f / red[0];
  for (int n = t; n < N_; n += 256) q[b * N_ + n] = (fmaxf(d[n], 0.f) + 1e-6f) * inv;
}

__global__ __launch_bounds__(256) void k_pmarg(const float* __restrict__ cosv,
    const float* __restrict__ temp_p, float* __restrict__ p){
  int b = blockIdx.x, t = threadIdx.x;
  __shared__ float red[256];
  float temp = fmaxf(temp_p[0], 0.01f);
  float inv_t = 1.f / temp;
  const float* cb = cosv + (size_t)b * N_;
  float m = -1e30f;
  for (int n = t; n < N_; n += 256) m = fmaxf(m, cb[n] * inv_t);
  red[t] = m; __syncthreads();
  for (int o = 128; o > 0; o >>= 1){ if (t < o) red[t] = fmaxf(red[t], red[t + o]); __syncthreads(); }
  m = red[0]; __syncthreads();
  float s = 0.f;
  for (int n = t; n < N_; n += 256) s += expf(cb[n] * inv_t - m);
  red[t] = s; __syncthreads();
  for (int o = 128; o > 0; o >>= 1){ if (t < o) red[t] += red[t + o]; __syncthreads(); }
  float invs = 1.f / red[0];
  for (int n = t; n < N_; n += 256) p[b * N_ + n] = expf(cb[n] * inv_t - m) * invs;
}

__global__ __launch_bounds__(256) void k_zero(float* __restrict__ p, int n){
  int i = blockIdx.x * 256 + threadIdx.x;
  if (i < n) p[i] = 0.f;
}

// ---------- K = exp(20*(sn sn^T - 1)) bf16 via MFMA + column sums ----------
__global__ __launch_bounds__(256) void k_kgen(
    const u16* __restrict__ snb, u16* __restrict__ Kp, float* __restrict__ colsum)
{
  int b = blockIdx.z;
  int m0 = blockIdx.x << 7, n0 = blockIdx.y << 7;
  int t = threadIdx.x;
  int lane = t & 63, w = t >> 6;
  int wr = w >> 1, wc = w & 1;
  __shared__ __align__(16) u16 Al[128 * 64];
  __shared__ __align__(16) u16 Bl[128 * 64];
  __shared__ float cs[128];
  if (t < 128) cs[t] = 0.f;
  f32x4 zero = {0.f, 0.f, 0.f, 0.f};
  f32x4 acc[4][4];
  #pragma unroll
  for (int i = 0; i < 4; i++){
    #pragma unroll
    for (int j = 0; j < 4; j++) acc[i][j] = zero;
  }
  const u16* sb = snb + (size_t)b * N_ * C_;
  const u16* ga = sb + (size_t)m0 * C_;
  const u16* gb = sb + (size_t)n0 * C_;
  for (int kt = 0; kt < C_; kt += 64){
    stage_tile(ga + kt, C_, Al, t);
    stage_tile(gb + kt, C_, Bl, t);
    __syncthreads();
    #pragma unroll
    for (int kh = 0; kh < 2; kh++){
      short8 af[4], bfv[4];
      #pragma unroll
      for (int i = 0; i < 4; i++){
        af[i]  = frag_ld(Al, wr * 64 + i * 16 + (lane & 15), kh * 4 + (lane >> 4));
        bfv[i] = frag_ld(Bl, wc * 64 + i * 16 + (lane & 15), kh * 4 + (lane >> 4));
      }
      #pragma unroll
      for (int i = 0; i < 4; i++){
        #pragma unroll
        for (int j = 0; j < 4; j++)
          acc[i][j] = MFMA_BF16(af[i], bfv[j], acc[i][j]);
      }
    }
    __syncthreads();
  }
  u16* Kb = Kp + (size_t)b * N_ * N_;
  int rbase = (lane >> 4) * 4;
  #pragma unroll
  for (int j = 0; j < 4; j++){
    int nc = wc * 64 + j * 16 + (lane & 15);
    float csum = 0.f;
    #pragma unroll
    for (int i = 0; i < 4; i++){
      int mr = m0 + wr * 64 + i * 16 + rbase;
      #pragma unroll
      for (int r = 0; r < 4; r++){
        float e = expf(20.f * (acc[i][j][r] - 1.f));
        u16 pk = f2bf(e);
        Kb[(size_t)(mr + r) * N_ + n0 + nc] = pk;
        csum += bf2f(pk);
      }
    }
    atomicAdd(&cs[nc], csum);
  }
  __syncthreads();
  if (t < 128) atomicAdd(&colsum[b * N_ + n0 + t], cs[t]);
}

__global__ __launch_bounds__(256) void k_div(
    const float* __restrict__ marg, const float* __restrict__ denom, float* __restrict__ outp){
  int i = blockIdx.x * 256 + threadIdx.x;
  if (i < B_ * N_) outp[i] = marg[i] / (denom[i] + 1e-8f);
}

// ---------- out[r] = marg[r] / (K_row_r . x + 1e-8)  (K symmetric) ----------
__global__ __launch_bounds__(256) void k_mv(
    const u16* __restrict__ Kp, const float* __restrict__ x,
    const float* __restrict__ marg, float* __restrict__ outp)
{
  int r0 = blockIdx.x * 4;
  int b = r0 >> 12;
  int t = threadIdx.x, w = t >> 6, lane = t & 63;
  __shared__ __align__(16) float xs[N_];
  const float* xb = x + b * N_;
  for (int i = t; i < N_ / 4; i += 256)
    reinterpret_cast<float4*>(xs)[i] = reinterpret_cast<const float4*>(xb)[i];
  __syncthreads();
  int r = r0 + w;
  const u16* Kr = Kp + (size_t)b * N_ * N_ + (size_t)(r & (N_ - 1)) * N_;
  float acc = 0.f;
  #pragma unroll
  for (int p = 0; p < 8; p++){
    int idx = p * 512 + lane * 8;
    short8 kv = *reinterpret_cast<const short8*>(Kr + idx);
    float4 x0 = *reinterpret_cast<const float4*>(xs + idx);
    float4 x1 = *reinterpret_cast<const float4*>(xs + idx + 4);
    acc += bf2f((u16)kv[0]) * x0.x + bf2f((u16)kv[1]) * x0.y
         + bf2f((u16)kv[2]) * x0.z + bf2f((u16)kv[3]) * x0.w
         + bf2f((u16)kv[4]) * x1.x + bf2f((u16)kv[5]) * x1.y
         + bf2f((u16)kv[6]) * x1.z + bf2f((u16)kv[7]) * x1.w;
  }
  for (int o = 32; o > 0; o >>= 1) acc += __shfl_down(acc, o);
  if (lane == 0) outp[r] = marg[r] / (acc + 1e-8f);
}

// ---------- usrcT[c][n] = srcT[c][n] * u[n] ----------
__global__ __launch_bounds__(256) void k_uscale(
    const u16* __restrict__ srcT, const float* __restrict__ uu, u16* __restrict__ usrcT)
{
  int i = blockIdx.x * 256 + threadIdx.x;   // 8-elem group
  int n8 = i & (N_ / 8 - 1);
  int row = i >> 9;                          // b*C + c
  int b = row >> 8;
  const u16* s = srcT + (size_t)row * N_ + n8 * 8;
  short8 v = *reinterpret_cast<const short8*>(s);
  const float* ub = uu + b * N_ + n8 * 8;
  short8 o;
  #pragma unroll
  for (int q = 0; q < 8; q++) o[q] = (short)f2bf(bf2f((u16)v[q]) * ub[q]);
  *reinterpret_cast<short8*>(usrcT + (size_t)row * N_ + n8 * 8) = o;
}

// ---------- part[ks][m][c] = sum_{n in ks chunk} K[m][n] * usrc[n][c]  (MFMA) ----------
__global__ __launch_bounds__(256) void k_full(
    const u16* __restrict__ Kp, const u16* __restrict__ usrcT,
    float* __restrict__ part0, float* __restrict__ part1)
{
  int m0 = blockIdx.x << 7;
  int c0 = blockIdx.y << 7;
  int b = blockIdx.z >> 1, ks = blockIdx.z & 1;
  int t = threadIdx.x, lane = t & 63, w = t >> 6;
  int wr = w >> 1, wc = w & 1;
  __shared__ __align__(16) u16 Al[128 * 64];
  __shared__ __align__(16) u16 Bl[128 * 64];
  f32x4 zero = {0.f, 0.f, 0.f, 0.f};
  f32x4 acc[4][4];
  #pragma unroll
  for (int i = 0; i < 4; i++){
    #pragma unroll
    for (int j = 0; j < 4; j++) acc[i][j] = zero;
  }
  const u16* ka = Kp + (size_t)b * N_ * N_ + (size_t)m0 * N_ + ks * (N_ / KSPLIT);
  const u16* ub = usrcT + (size_t)b * C_ * N_ + (size_t)c0 * N_ + ks * (N_ / KSPLIT);
  for (int kt = 0; kt < N_ / KSPLIT; kt += 64){
    stage_tile(ka + kt, N_, Al, t);
    stage_tile(ub + kt, N_, Bl, t);
    __syncthreads();
    #pragma unroll
    for (int kh = 0; kh < 2; kh++){
      short8 af[4], bfv[4];
      #pragma unroll
      for (int i = 0; i < 4; i++){
        af[i]  = frag_ld(Al, wr * 64 + i * 16 + (lane & 15), kh * 4 + (lane >> 4));
        bfv[i] = frag_ld(Bl, wc * 64 + i * 16 + (lane & 15), kh * 4 + (lane >> 4));
      }
      #pragma unroll
      for (int i = 0; i < 4; i++){
        #pragma unroll
        for (int j = 0; j < 4; j++)
          acc[i][j] = MFMA_BF16(af[i], bfv[j], acc[i][j]);
      }
    }
    __syncthreads();
  }
  float* P = ks ? part1 : part0;
  #pragma unroll
  for (int i = 0; i < 4; i++){
    int mr = m0 + wr * 64 + i * 16 + (lane >> 4) * 4;
    #pragma unroll
    for (int j = 0; j < 4; j++){
      int cc = c0 + wc * 64 + j * 16 + (lane & 15);
      #pragma unroll
      for (int r = 0; r < 4; r++)
        P[(size_t)((b << 12) + mr + r) * C_ + cc] = acc[i][j][r];
    }
  }
}

// ---------- out_feat = img + 1x1conv(vv * (part0+part1)) ----------
__global__ __launch_bounds__(256) void k_opconv(
    const float* __restrict__ opw, const float* __restrict__ opb,
    const float* __restrict__ p0, const float* __restrict__ p1,
    const float* __restrict__ vvv,
    const float* __restrict__ img, float* __restrict__ outf)
{
  int b = blockIdx.z;
  int n0 = blockIdx.x * GT;
  int co0 = blockIdx.y * GT;
  int t = threadIdx.x, tx = t & 15, ty = t >> 4;
  __shared__ __align__(16) float Ws[GK][68];
  __shared__ __align__(16) float Fs[GK][68];
  __shared__ float vs_n[GT];
  if (t < GT) vs_n[t] = vvv[b * N_ + n0 + t];
  __syncthreads();
  float acc[4][4] = {};
  for (int c0 = 0; c0 < C_; c0 += GK){
    for (int e = t; e < GT * GK; e += 256){
      int a_ = e >> 5, i_ = e & 31;
      Ws[i_][a_] = opw[(size_t)(co0 + a_) * C_ + c0 + i_];
      size_t idx = (size_t)((b << 12) + n0 + a_) * C_ + c0 + i_;
      Fs[i_][a_] = (p0[idx] + p1[idx]) * vs_n[a_];
    }
    __syncthreads();
    #pragma unroll
    for (int kk = 0; kk < GK; kk++){
      float4 a4 = *reinterpret_cast<const float4*>(&Ws[kk][ty * 4]);
      float4 b4 = *reinterpret_cast<const float4*>(&Fs[kk][tx * 4]);
      float ar[4] = {a4.x, a4.y, a4.z, a4.w};
      float br[4] = {b4.x, b4.y, b4.z, b4.w};
      #pragma unroll
      for (int i = 0; i < 4; i++)
        #pragma unroll
        for (int j = 0; j < 4; j++)
          acc[i][j] += ar[i] * br[j];
    }
    __syncthreads();
  }
  for (int i = 0; i < 4; i++){
    int co = co0 + ty * 4 + i;
    const float4 iv = *reinterpret_cast<const float4*>(&img[(size_t)(b * C_ + co) * N_ + n0 + tx * 4]);
    float ob = opb[co];
    float4 o;
    o.x = iv.x + acc[i][0] + ob; o.y = iv.y + acc[i][1] + ob;
    o.z = iv.z + acc[i][2] + ob; o.w = iv.w + acc[i][3] + ob;
    *reinterpret_cast<float4*>(&outf[(size_t)(b * C_ + co) * N_ + n0 + tx * 4]) = o;
  }
}

// ---------- 3x3 conv 256->128, pad 1 ----------
__global__ __launch_bounds__(256) void k_conv3(
    const float* __restrict__ inf, const float* __restrict__ w,
    const float* __restrict__ bias, float* __restrict__ mid)
{
  int b = blockIdx.z;
  int y = blockIdx.x;         // 0..63
  int co0 = blockIdx.y * 64;  // 0 or 64
  int t = threadIdx.x, tx = t & 15, ty = t >> 4;
  __shared__ float in_s[8][3][68];
  __shared__ float w_s[64][73];
  float acc[4][4] = {};
  for (int c0 = 0; c0 < C_; c0 += 8){
    for (int e = t; e < 8 * 3 * 66; e += 256){
      int ci = e / 198, rem = e % 198, ry = rem / 66, xx = rem % 66;
      int yy = y + ry - 1, xg = xx - 1;
      float v = 0.f;
      if (yy >= 0 && yy < 64 && xg >= 0 && xg < 64)
        v = inf[(size_t)(b * C_ + c0 + ci) * N_ + yy * 64 + xg];
      in_s[ci][ry][xx] = v;
    }
    for (int e = t; e < 64 * 72; e += 256){
      int co = e / 72, r = e % 72;
      w_s[co][r] = w[(size_t)(co0 + co) * C_ * 9 + c0 * 9 + r];
    }
    __syncthreads();
    for (int ci = 0; ci < 8; ci++){
      #pragma unroll
      for (int ky = 0; ky < 3; ky++){
        float iv[6];
        #pragma unroll
        for (int q = 0; q < 6; q++) iv[q] = in_s[ci][ky][tx * 4 + q];
        #pragma unroll
        for (int kx = 0; kx < 3; kx++){
          #pragma unroll
          for (int i = 0; i < 4; i++){
            float wv = w_s[ty * 4 + i][ci * 9 + ky * 3 + kx];
            #pragma unroll
            for (int j = 0; j < 4; j++) acc[i][j] += wv * iv[j + kx];
          }
        }
      }
    }
    __syncthreads();
  }
  for (int i = 0; i < 4; i++){
    int co = co0 + ty * 4 + i;
    float bv = bias[co];
    float4 o = {acc[i][0] + bv, acc[i][1] + bv, acc[i][2] + bv, acc[i][3] + bv};
    *reinterpret_cast<float4*>(&mid[(size_t)(b * CH_ + co) * N_ + y * 64 + tx * 4]) = o;
  }
}

// ---------- batchnorm stats over (B,H,W) per channel ----------
__global__ __launch_bounds__(256) void k_bnstats(const float* __restrict__ mid, float* __restrict__ stats){
  int ch = blockIdx.x, t = threadIdx.x;
  __shared__ float r1[256], r2[256];
  float s1 = 0.f, s2 = 0.f;
  for (int i = t; i < B_ * N_; i += 256){
    int b = i >> 12, n = i & (N_ - 1);
    float v = mid[(size_t)(b * CH_ + ch) * N_ + n];
    s1 += v; s2 += v * v;
  }
  r1[t] = s1; r2[t] = s2; __syncthreads();
  for (int o = 128; o > 0; o >>= 1){
    if (t < o){ r1[t] += r1[t + o]; r2[t] += r2[t + o]; }
    __syncthreads();
  }
  if (t == 0){
    float mean = r1[0] / (float)(B_ * N_);
    float var = r2[0] / (float)(B_ * N_) - mean * mean;
    stats[ch * 2] = mean;
    stats[ch * 2 + 1] = rsqrtf(var + 1e-5f);
  }
}

// ---------- relu(bn(mid)) -> 1x1 conv to 2 channels ----------
__global__ __launch_bounds__(256) void k_head(
    const float* __restrict__ mid, const float* __restrict__ stats,
    const float* __restrict__ g, const float* __restrict__ bb,
    const float* __restrict__ w2, const float* __restrict__ b2,
    float* __restrict__ outp)
{
  int idx = blockIdx.x * 256 + threadIdx.x;
  int b = idx >> 12, n = idx & (N_ - 1);
  float a0 = 0.f, a1 = 0.f;
  for (int ch = 0; ch < CH_; ch++){
    float v = mid[(size_t)(b * CH_ + ch) * N_ + n];
    float rr = (v - stats[ch * 2]) * stats[ch * 2 + 1] * g[ch] + bb[ch];
    rr = fmaxf(rr, 0.f);
    a0 += w2[ch] * rr;
    a1 += w2[CH_ + ch] * rr;
  }
  outp[(size_t)(b * 2) * N_ + n] = a0 + b2[0];
  outp[(size_t)(b * 2 + 1) * N_ + n] = a1 + b2[1];
}

extern "C" void kernel_launch(void* const* d_in, const int* in_sizes, int n_in,
                              void* d_out, int out_size, void* d_ws, size_t ws_size,
                              hipStream_t stream)
{
  const float* img   = (const float*)d_in[0];
  const float* txt   = (const float*)d_in[1];
  const float* dens  = (const float*)d_in[2];
  const float* tp_w  = (const float*)d_in[3];
  const float* tp_b  = (const float*)d_in[4];
  const float* wv    = (const float*)d_in[9];
  const float* bv    = (const float*)d_in[10];
  const float* wo    = (const float*)d_in[11];
  const float* bo    = (const float*)d_in[12];
  const float* ln_g  = (const float*)d_in[13];
  const float* ln_b  = (const float*)d_in[14];
  const float* op_w  = (const float*)d_in[15];
  const float* op_b  = (const float*)d_in[16];
  const float* hm1_w = (const float*)d_in[17];
  const float* hm1_b = (const float*)d_in[18];
  const float* hm_g  = (const float*)d_in[19];
  const float* hm_b  = (const float*)d_in[20];
  const float* hm2_w = (const float*)d_in[21];
  const float* hm2_b = (const float*)d_in[22];
  const float* hv1_w = (const float*)d_in[23];
  const float* hv1_b = (const float*)d_in[24];
  const float* hv_g  = (const float*)d_in[25];
  const float* hv_b  = (const float*)d_in[26];
  const float* hv2_w = (const float*)d_in[27];
  const float* hv2_b = (const float*)d_in[28];
  const float* temp  = (const float*)d_in[29];

  char* wsb = (char*)d_ws;
  size_t off = 0;
  auto alloc = [&](size_t bytes) -> void* {
    void* p = wsb + off;
    off += (bytes + 255) & ~(size_t)255;
    return p;
  };
  u16*   Km     = (u16*)  alloc((size_t)B_ * N_ * N_ * sizeof(u16));   // 67.1 MB
  u16*   snb16  = (u16*)  alloc((size_t)B_ * N_ * C_ * sizeof(u16));   // 4.19 MB (aliased by part0 later)
  u16*   srcT16 = (u16*)  alloc((size_t)B_ * C_ * N_ * sizeof(u16));   // 4.19 MB (aliased by part0 later)
  u16*   usrcT  = (u16*)  alloc((size_t)B_ * C_ * N_ * sizeof(u16));   // 4.19 MB
  float* part1  = (float*)alloc((size_t)B_ * N_ * C_ * sizeof(float)); // 8.39 MB (aliased by mid later)
  float* txt_emb= (float*)alloc(B_ * C_ * sizeof(float));
  float* attn_c = (float*)alloc(B_ * C_ * sizeof(float));
  float* txt_n  = (float*)alloc(B_ * C_ * sizeof(float));
  float* cosv   = (float*)alloc(B_ * N_ * sizeof(float));
  float* qm     = (float*)alloc(B_ * N_ * sizeof(float));
  float* pm     = (float*)alloc(B_ * N_ * sizeof(float));
  float* uu     = (float*)alloc(B_ * N_ * sizeof(float));
  float* vvv    = (float*)alloc(B_ * N_ * sizeof(float));
  float* colsum = (float*)alloc(B_ * N_ * sizeof(float));
  float* stats  = (float*)alloc(CH_ * 2 * sizeof(float));

  // aliases: part0 over (snb16 + srcT16), mid over part1 — lifetimes disjoint
  float* part0 = (float*)snb16;
  float* mid   = part1;

  float* outf  = (float*)d_out;
  float* outhm = outf + (size_t)B_ * C_ * N_;
  float* outhv = outhm + (size_t)B_ * 2 * N_;

  k_text<<<B_, 256, 0, stream>>>(txt, tp_w, tp_b, wv, bv, wo, bo, txt_emb, attn_c, txt_n);
  k_source<<<dim3(N_ / TN, B_), 256, 0, stream>>>(img, attn_c, ln_g, ln_b, txt_n, srcT16, snb16, cosv);
  k_qmarg<<<B_, 256, 0, stream>>>(dens, qm);
  k_pmarg<<<B_, 256, 0, stream>>>(cosv, temp, pm);
  k_zero<<<(B_ * N_ + 255) / 256, 256, 0, stream>>>(colsum, B_ * N_);
  k_kgen<<<dim3(N_ / 128, N_ / 128, B_), 256, 0, stream>>>(snb16, Km, colsum);
  // Sinkhorn (K symmetric: K^T x == K x)
  k_div<<<(B_ * N_ + 255) / 256, 256, 0, stream>>>(qm, colsum, vvv);        // vv1
  k_mv<<<B_ * N_ / 4, 256, 0, stream>>>(Km, vvv, pm, uu);                   // u1
  k_mv<<<B_ * N_ / 4, 256, 0, stream>>>(Km, uu, qm, vvv);                   // vv2
  k_mv<<<B_ * N_ / 4, 256, 0, stream>>>(Km, vvv, pm, uu);                   // u2
  k_mv<<<B_ * N_ / 4, 256, 0, stream>>>(Km, uu, qm, vvv);                   // vv3
  k_mv<<<B_ * N_ / 4, 256, 0, stream>>>(Km, vvv, pm, uu);                   // u3
  k_uscale<<<(B_ * C_ * N_ / 8 + 255) / 256, 256, 0, stream>>>(srcT16, uu, usrcT);
  k_full<<<dim3(N_ / 128, C_ / 128, B_ * KSPLIT), 256, 0, stream>>>(Km, usrcT, part0, part1);
  k_opconv<<<dim3(N_ / GT, C_ / GT, B_), 256, 0, stream>>>(op_w, op_b, part0, part1, vvv, img, outf);
  // hm head
  k_conv3<<<dim3(64, 2, B_), 256, 0, stream>>>(outf, hm1_w, hm1_b, mid);
  k_bnstats<<<CH_, 256, 0, stream>>>(mid, stats);
  k_head<<<B_ * N_ / 256, 256, 0, stream>>>(mid, stats, hm_g, hm_b, hm2_w, hm2_b, outhm);
  // hv head
  k_conv3<<<dim3(64, 2, B_), 256, 0, stream>>>(outf, hv1_w, hv1_b, mid);
  k_bnstats<<<CH_, 256, 0, stream>>>(mid, stats);
  k_head<<<B_ * N_ / 256, 256, 0, stream>>>(mid, stats, hv_g, hv_b, hv2_w, hv2_b, outhv);
}

// Round 3
// 323.632 us; speedup vs baseline: 5.2565x; 2.2614x over previous
//
#include <hip/hip_runtime.h>
#include <math.h>

#define B_ 2
#define C_ 256
#define N_ 4096
#define TXT_ 512
#define CH_ 128
#define TN 32
#define GT 64
#define GK 32
#define KSPLIT 2
#define PXR 4224          // 64 * 66 padded-pixel rows per batch
#define PXPAD 96          // halo pad rows each side
#define PXTOT (PXR + 2 * PXPAD)

typedef unsigned short u16;
typedef __attribute__((ext_vector_type(8))) short short8;
typedef __attribute__((ext_vector_type(4))) float f32x4;

__device__ __forceinline__ float bf2f(u16 v){
  union { unsigned u; float f; } w; w.u = ((unsigned)v) << 16; return w.f;
}
__device__ __forceinline__ u16 f2bf(float f){
  union { float f; unsigned u; } w; w.f = f;
  unsigned r = w.u + 0x7fffu + ((w.u >> 16) & 1u);
  return (u16)(r >> 16);
}

#define MFMA_BF16(a,b,c) __builtin_amdgcn_mfma_f32_16x16x32_bf16(a,b,c,0,0,0)

// Stage a 128-row x 64-col bf16 tile from global (row stride `stride` elems) into
// LDS via global_load_lds (linear dest). Source addresses are pre-swizzled so the
// LDS holds the XOR-swizzled tile; frag_ld applies the same XOR on read.
__device__ __forceinline__ void stage_tile(const u16* __restrict__ g, int stride, u16* lds, int t)
{
  #pragma unroll
  for (int q = 0; q < 4; q++){
    int e = q * 256 + t;          // 16B unit index
    int row = e >> 3;             // 8 units per 128B row
    int slot = e & 7;
    const u16* gp = g + (size_t)row * stride + ((slot ^ (row & 7)) << 3);
    u16* lp = lds + (size_t)e * 8;
    __builtin_amdgcn_global_load_lds((const __attribute__((address_space(1))) void*)gp,
                                     (__attribute__((address_space(3))) void*)lp, 16, 0, 0);
  }
}

__device__ __forceinline__ short8 frag_ld(const u16* lds, int row, int slot)
{
  return *(const short8*)(lds + row * 64 + ((slot ^ (row & 7)) << 3));
}

// ---------- text pipeline: txt_emb, attn constant (v@wo^T+bo), txt_n ----------
__global__ __launch_bounds__(256) void k_text(
    const float* __restrict__ txt, const float* __restrict__ tpw,
    const float* __restrict__ tpb, const float* __restrict__ wv,
    const float* __restrict__ bv, const float* __restrict__ wo,
    const float* __restrict__ bo,
    float* __restrict__ txt_emb, float* __restrict__ attn_c, float* __restrict__ txt_n)
{
  int b = blockIdx.x, t = threadIdx.x;
  __shared__ float te[C_], vs[C_], red[C_];
  const float* tb = txt + b * TXT_;
  const float* wr = tpw + (size_t)t * TXT_;
  float s = 0.f;
  for (int j = 0; j < TXT_; j++) s += tb[j] * wr[j];
  s += tpb[t];
  te[t] = s;
  txt_emb[b * C_ + t] = s;
  __syncthreads();
  float sv = 0.f;
  const float* wvr = wv + (size_t)t * C_;
  for (int j = 0; j < C_; j++) sv += te[j] * wvr[j];
  sv += bv[t];
  vs[t] = sv;
  __syncthreads();
  float sa = 0.f;
  const float* wor = wo + (size_t)t * C_;
  for (int j = 0; j < C_; j++) sa += vs[j] * wor[j];
  sa += bo[t];
  attn_c[b * C_ + t] = sa;
  red[t] = te[t] * te[t];
  __syncthreads();
  for (int o = 128; o > 0; o >>= 1){ if (t < o) red[t] += red[t + o]; __syncthreads(); }
  float nrm = sqrtf(red[0]);
  float inv = 1.f / fmaxf(nrm, 1e-12f);
  txt_n[b * C_ + t] = te[t] * inv;
}

// ---------- source (residual+LN) -> srcT bf16 [C][N], snb bf16 [N][C], cos ----------
__global__ __launch_bounds__(256) void k_source(
    const float* __restrict__ img, const float* __restrict__ attn_c,
    const float* __restrict__ ln_g, const float* __restrict__ ln_b,
    const float* __restrict__ txt_n,
    u16* __restrict__ srcT, u16* __restrict__ snb, float* __restrict__ cosv)
{
  int b = blockIdx.y;
  int n0 = blockIdx.x * TN;
  int t = threadIdx.x;
  __shared__ float x[C_][TN + 1];
  __shared__ float ps[8][TN];
  __shared__ float ps2[8][TN];
  __shared__ float ac_s[C_], g_s[C_], bb_s[C_], tn_s[C_];
  __shared__ float mean_s[TN], rstd_s[TN], rn_s[TN];
  ac_s[t] = attn_c[b * C_ + t];
  g_s[t]  = ln_g[t];
  bb_s[t] = ln_b[t];
  tn_s[t] = txt_n[b * C_ + t];
  const float* ib = img + (size_t)b * C_ * N_ + n0;
  for (int k = 0; k < TN; k++){
    int e = t + k * 256;
    int c = e >> 5, nn = e & 31;
    x[c][nn] = ib[(size_t)c * N_ + nn];
  }
  __syncthreads();
  for (int k = 0; k < TN; k++){
    int e = t + k * 256;
    int c = e >> 5, nn = e & 31;
    x[c][nn] += ac_s[c];
  }
  __syncthreads();
  {
    int p = t >> 5, nn = t & 31;
    float s1 = 0.f, s2 = 0.f;
    for (int j = 0; j < 32; j++){
      float v = x[p + 8 * j][nn];
      s1 += v; s2 += v * v;
    }
    ps[p][nn] = s1; ps2[p][nn] = s2;
  }
  __syncthreads();
  if (t < TN){
    float S1 = 0.f, S2 = 0.f;
    for (int pp = 0; pp < 8; pp++){ S1 += ps[pp][t]; S2 += ps2[pp][t]; }
    float mean = S1 * (1.f / C_);
    float var = S2 * (1.f / C_) - mean * mean;
    mean_s[t] = mean;
    rstd_s[t] = rsqrtf(var + 1e-5f);
  }
  __syncthreads();
  for (int k = 0; k < TN; k++){
    float sval = (x[t][k] - mean_s[k]) * rstd_s[k] * g_s[t] + bb_s[t];
    x[t][k] = sval;
  }
  for (int kq = 0; kq < TN; kq += 4){
    ushort4 pkv;
    pkv.x = f2bf(x[t][kq + 0]);
    pkv.y = f2bf(x[t][kq + 1]);
    pkv.z = f2bf(x[t][kq + 2]);
    pkv.w = f2bf(x[t][kq + 3]);
    *reinterpret_cast<ushort4*>(&srcT[(size_t)(b * C_ + t) * N_ + n0 + kq]) = pkv;
  }
  __syncthreads();
  {
    int p = t >> 5, nn = t & 31;
    float s2 = 0.f, sd = 0.f;
    for (int j = 0; j < 32; j++){
      int c = p + 8 * j;
      float v = x[c][nn];
      s2 += v * v; sd += v * tn_s[c];
    }
    ps[p][nn] = s2; ps2[p][nn] = sd;
  }
  __syncthreads();
  if (t < TN){
    float S2 = 0.f, SD = 0.f;
    for (int pp = 0; pp < 8; pp++){ S2 += ps[pp][t]; SD += ps2[pp][t]; }
    float nrm = sqrtf(S2);
    float rn = 1.f / fmaxf(nrm, 1e-12f);
    rn_s[t] = rn;
    cosv[(b << 12) + n0 + t] = SD * rn;
  }
  __syncthreads();
  for (int k = 0; k < TN; k++){
    snb[(size_t)((b << 12) + n0 + k) * C_ + t] = f2bf(x[t][k] * rn_s[k]);
  }
}

// ---------- marginals ----------
__global__ __launch_bounds__(256) void k_qmarg(const float* __restrict__ dens, float* __restrict__ q){
  int b = blockIdx.x, t = threadIdx.x;
  __shared__ float red[256];
  const float* d = dens + (size_t)b * N_;
  float s = 0.f;
  for (int n = t; n < N_; n += 256) s += fmaxf(d[n], 0.f) + 1e-6f;
  red[t] = s; __syncthreads();
  for (int o = 128; o > 0; o >>= 1){ if (t < o) red[t] += red[t + o]; __syncthreads(); }
  float inv = 1.f / red[0];
  for (int n = t; n < N_; n += 256) q[b * N_ + n] = (fmaxf(d[n], 0.f) + 1e-6f) * inv;
}

__global__ __launch_bounds__(256) void k_pmarg(const float* __restrict__ cosv,
    const float* __restrict__ temp_p, float* __restrict__ p){
  int b = blockIdx.x, t = threadIdx.x;
  __shared__ float red[256];
  float temp = fmaxf(temp_p[0], 0.01f);
  float inv_t = 1.f / temp;
  const float* cb = cosv + (size_t)b * N_;
  float m = -1e30f;
  for (int n = t; n < N_; n += 256) m = fmaxf(m, cb[n] * inv_t);
  red[t] = m; __syncthreads();
  for (int o = 128; o > 0; o >>= 1){ if (t < o) red[t] = fmaxf(red[t], red[t + o]); __syncthreads(); }
  m = red[0]; __syncthreads();
  float s = 0.f;
  for (int n = t; n < N_; n += 256) s += expf(cb[n] * inv_t - m);
  red[t] = s; __syncthreads();
  for (int o = 128; o > 0; o >>= 1){ if (t < o) red[t] += red[t + o]; __syncthreads(); }
  float invs = 1.f / red[0];
  for (int n = t; n < N_; n += 256) p[b * N_ + n] = expf(cb[n] * inv_t - m) * invs;
}

__global__ __launch_bounds__(256) void k_zero(float* __restrict__ p, int n){
  int i = blockIdx.x * 256 + threadIdx.x;
  if (i < n) p[i] = 0.f;
}

// ---------- K = exp(20*(sn sn^T - 1)) bf16 via MFMA + column sums ----------
__global__ __launch_bounds__(256) void k_kgen(
    const u16* __restrict__ snb, u16* __restrict__ Kp, float* __restrict__ colsum)
{
  int b = blockIdx.z;
  int m0 = blockIdx.x << 7, n0 = blockIdx.y << 7;
  int t = threadIdx.x;
  int lane = t & 63, w = t >> 6;
  int wr = w >> 1, wc = w & 1;
  __shared__ __align__(16) u16 Al[128 * 64];
  __shared__ __align__(16) u16 Bl[128 * 64];
  __shared__ float cs[128];
  if (t < 128) cs[t] = 0.f;
  f32x4 zero = {0.f, 0.f, 0.f, 0.f};
  f32x4 acc[4][4];
  #pragma unroll
  for (int i = 0; i < 4; i++){
    #pragma unroll
    for (int j = 0; j < 4; j++) acc[i][j] = zero;
  }
  const u16* sb = snb + (size_t)b * N_ * C_;
  const u16* ga = sb + (size_t)m0 * C_;
  const u16* gb = sb + (size_t)n0 * C_;
  for (int kt = 0; kt < C_; kt += 64){
    stage_tile(ga + kt, C_, Al, t);
    stage_tile(gb + kt, C_, Bl, t);
    __syncthreads();
    #pragma unroll
    for (int kh = 0; kh < 2; kh++){
      short8 af[4], bfv[4];
      #pragma unroll
      for (int i = 0; i < 4; i++){
        af[i]  = frag_ld(Al, wr * 64 + i * 16 + (lane & 15), kh * 4 + (lane >> 4));
        bfv[i] = frag_ld(Bl, wc * 64 + i * 16 + (lane & 15), kh * 4 + (lane >> 4));
      }
      #pragma unroll
      for (int i = 0; i < 4; i++){
        #pragma unroll
        for (int j = 0; j < 4; j++)
          acc[i][j] = MFMA_BF16(af[i], bfv[j], acc[i][j]);
      }
    }
    __syncthreads();
  }
  u16* Kb = Kp + (size_t)b * N_ * N_;
  int rbase = (lane >> 4) * 4;
  #pragma unroll
  for (int j = 0; j < 4; j++){
    int nc = wc * 64 + j * 16 + (lane & 15);
    float csum = 0.f;
    #pragma unroll
    for (int i = 0; i < 4; i++){
      int mr = m0 + wr * 64 + i * 16 + rbase;
      #pragma unroll
      for (int r = 0; r < 4; r++){
        float e = expf(20.f * (acc[i][j][r] - 1.f));
        u16 pk = f2bf(e);
        Kb[(size_t)(mr + r) * N_ + n0 + nc] = pk;
        csum += bf2f(pk);
      }
    }
    atomicAdd(&cs[nc], csum);
  }
  __syncthreads();
  if (t < 128) atomicAdd(&colsum[b * N_ + n0 + t], cs[t]);
}

__global__ __launch_bounds__(256) void k_div(
    const float* __restrict__ marg, const float* __restrict__ denom, float* __restrict__ outp){
  int i = blockIdx.x * 256 + threadIdx.x;
  if (i < B_ * N_) outp[i] = marg[i] / (denom[i] + 1e-8f);
}

// ---------- out[r] = marg[r] / (K_row_r . x + 1e-8)  (K symmetric) ----------
__global__ __launch_bounds__(256) void k_mv(
    const u16* __restrict__ Kp, const float* __restrict__ x,
    const float* __restrict__ marg, float* __restrict__ outp)
{
  int r0 = blockIdx.x * 4;
  int b = r0 >> 12;
  int t = threadIdx.x, w = t >> 6, lane = t & 63;
  __shared__ __align__(16) float xs[N_];
  const float* xb = x + b * N_;
  for (int i = t; i < N_ / 4; i += 256)
    reinterpret_cast<float4*>(xs)[i] = reinterpret_cast<const float4*>(xb)[i];
  __syncthreads();
  int r = r0 + w;
  const u16* Kr = Kp + (size_t)b * N_ * N_ + (size_t)(r & (N_ - 1)) * N_;
  float acc = 0.f;
  #pragma unroll
  for (int p = 0; p < 8; p++){
    int idx = p * 512 + lane * 8;
    short8 kv = *reinterpret_cast<const short8*>(Kr + idx);
    float4 x0 = *reinterpret_cast<const float4*>(xs + idx);
    float4 x1 = *reinterpret_cast<const float4*>(xs + idx + 4);
    acc += bf2f((u16)kv[0]) * x0.x + bf2f((u16)kv[1]) * x0.y
         + bf2f((u16)kv[2]) * x0.z + bf2f((u16)kv[3]) * x0.w
         + bf2f((u16)kv[4]) * x1.x + bf2f((u16)kv[5]) * x1.y
         + bf2f((u16)kv[6]) * x1.z + bf2f((u16)kv[7]) * x1.w;
  }
  for (int o = 32; o > 0; o >>= 1) acc += __shfl_down(acc, o);
  if (lane == 0) outp[r] = marg[r] / (acc + 1e-8f);
}

// ---------- usrcT[c][n] = srcT[c][n] * u[n] ----------
__global__ __launch_bounds__(256) void k_uscale(
    const u16* __restrict__ srcT, const float* __restrict__ uu, u16* __restrict__ usrcT)
{
  int i = blockIdx.x * 256 + threadIdx.x;
  int n8 = i & (N_ / 8 - 1);
  int row = i >> 9;
  int b = row >> 8;
  const u16* s = srcT + (size_t)row * N_ + n8 * 8;
  short8 v = *reinterpret_cast<const short8*>(s);
  const float* ub = uu + b * N_ + n8 * 8;
  short8 o;
  #pragma unroll
  for (int q = 0; q < 8; q++) o[q] = (short)f2bf(bf2f((u16)v[q]) * ub[q]);
  *reinterpret_cast<short8*>(usrcT + (size_t)row * N_ + n8 * 8) = o;
}

// ---------- part[ks][m][c] = sum_{n in ks chunk} K[m][n] * usrc[n][c]  (MFMA) ----------
__global__ __launch_bounds__(256) void k_full(
    const u16* __restrict__ Kp, const u16* __restrict__ usrcT,
    float* __restrict__ part0, float* __restrict__ part1)
{
  int m0 = blockIdx.x << 7;
  int c0 = blockIdx.y << 7;
  int b = blockIdx.z >> 1, ks = blockIdx.z & 1;
  int t = threadIdx.x, lane = t & 63, w = t >> 6;
  int wr = w >> 1, wc = w & 1;
  __shared__ __align__(16) u16 Al[128 * 64];
  __shared__ __align__(16) u16 Bl[128 * 64];
  f32x4 zero = {0.f, 0.f, 0.f, 0.f};
  f32x4 acc[4][4];
  #pragma unroll
  for (int i = 0; i < 4; i++){
    #pragma unroll
    for (int j = 0; j < 4; j++) acc[i][j] = zero;
  }
  const u16* ka = Kp + (size_t)b * N_ * N_ + (size_t)m0 * N_ + ks * (N_ / KSPLIT);
  const u16* ub = usrcT + (size_t)b * C_ * N_ + (size_t)c0 * N_ + ks * (N_ / KSPLIT);
  for (int kt = 0; kt < N_ / KSPLIT; kt += 64){
    stage_tile(ka + kt, N_, Al, t);
    stage_tile(ub + kt, N_, Bl, t);
    __syncthreads();
    #pragma unroll
    for (int kh = 0; kh < 2; kh++){
      short8 af[4], bfv[4];
      #pragma unroll
      for (int i = 0; i < 4; i++){
        af[i]  = frag_ld(Al, wr * 64 + i * 16 + (lane & 15), kh * 4 + (lane >> 4));
        bfv[i] = frag_ld(Bl, wc * 64 + i * 16 + (lane & 15), kh * 4 + (lane >> 4));
      }
      #pragma unroll
      for (int i = 0; i < 4; i++){
        #pragma unroll
        for (int j = 0; j < 4; j++)
          acc[i][j] = MFMA_BF16(af[i], bfv[j], acc[i][j]);
      }
    }
    __syncthreads();
  }
  float* P = ks ? part1 : part0;
  #pragma unroll
  for (int i = 0; i < 4; i++){
    int mr = m0 + wr * 64 + i * 16 + (lane >> 4) * 4;
    #pragma unroll
    for (int j = 0; j < 4; j++){
      int cc = c0 + wc * 64 + j * 16 + (lane & 15);
      #pragma unroll
      for (int r = 0; r < 4; r++)
        P[(size_t)((b << 12) + mr + r) * C_ + cc] = acc[i][j][r];
    }
  }
}

// ---------- out_feat = img + 1x1conv(vv * (part0+part1)) ----------
__global__ __launch_bounds__(256) void k_opconv(
    const float* __restrict__ opw, const float* __restrict__ opb,
    const float* __restrict__ p0, const float* __restrict__ p1,
    const float* __restrict__ vvv,
    const float* __restrict__ img, float* __restrict__ outf)
{
  int b = blockIdx.z;
  int n0 = blockIdx.x * GT;
  int co0 = blockIdx.y * GT;
  int t = threadIdx.x, tx = t & 15, ty = t >> 4;
  __shared__ __align__(16) float Ws[GK][68];
  __shared__ __align__(16) float Fs[GK][68];
  __shared__ float vs_n[GT];
  if (t < GT) vs_n[t] = vvv[b * N_ + n0 + t];
  __syncthreads();
  float acc[4][4] = {};
  for (int c0 = 0; c0 < C_; c0 += GK){
    for (int e = t; e < GT * GK; e += 256){
      int a_ = e >> 5, i_ = e & 31;
      Ws[i_][a_] = opw[(size_t)(co0 + a_) * C_ + c0 + i_];
      size_t idx = (size_t)((b << 12) + n0 + a_) * C_ + c0 + i_;
      Fs[i_][a_] = (p0[idx] + p1[idx]) * vs_n[a_];
    }
    __syncthreads();
    #pragma unroll
    for (int kk = 0; kk < GK; kk++){
      float4 a4 = *reinterpret_cast<const float4*>(&Ws[kk][ty * 4]);
      float4 b4 = *reinterpret_cast<const float4*>(&Fs[kk][tx * 4]);
      float ar[4] = {a4.x, a4.y, a4.z, a4.w};
      float br[4] = {b4.x, b4.y, b4.z, b4.w};
      #pragma unroll
      for (int i = 0; i < 4; i++)
        #pragma unroll
        for (int j = 0; j < 4; j++)
          acc[i][j] += ar[i] * br[j];
    }
    __syncthreads();
  }
  for (int i = 0; i < 4; i++){
    int co = co0 + ty * 4 + i;
    const float4 iv = *reinterpret_cast<const float4*>(&img[(size_t)(b * C_ + co) * N_ + n0 + tx * 4]);
    float ob = opb[co];
    float4 o;
    o.x = iv.x + acc[i][0] + ob; o.y = iv.y + acc[i][1] + ob;
    o.z = iv.z + acc[i][2] + ob; o.w = iv.w + acc[i][3] + ob;
    *reinterpret_cast<float4*>(&outf[(size_t)(b * C_ + co) * N_ + n0 + tx * 4]) = o;
  }
}

// ---------- transpose out_feat -> padded bf16 [b][px'][ci] ----------
__global__ __launch_bounds__(256) void k_tr(const float* __restrict__ outf, u16* __restrict__ inTp)
{
  int b = blockIdx.z;
  int c0 = blockIdx.y << 6;
  int px0 = blockIdx.x << 6;
  int t = threadIdx.x;
  __shared__ float tile[64][65];
  int tx = t & 63, ty4 = t >> 6;
  for (int cc = ty4; cc < 64; cc += 4)
    tile[cc][tx] = outf[((size_t)(b * C_) + c0 + cc) * N_ + px0 + tx];
  __syncthreads();
  int p = t >> 2, cg = (t & 3) << 4;
  int px = px0 + p;
  int y = px >> 6, x = px & 63;
  int pxp = y * 66 + x + 1;
  u16* dst = inTp + ((size_t)b * PXTOT + PXPAD + pxp) * C_ + c0 + cg;
  #pragma unroll
  for (int q = 0; q < 16; q += 4){
    ushort4 pk;
    pk.x = f2bf(tile[cg + q + 0][p]);
    pk.y = f2bf(tile[cg + q + 1][p]);
    pk.z = f2bf(tile[cg + q + 2][p]);
    pk.w = f2bf(tile[cg + q + 3][p]);
    *reinterpret_cast<ushort4*>(dst + q) = pk;
  }
}

// ---------- weights -> Wt[tap][co(256 fused)][ci] bf16, fused bias ----------
__global__ __launch_bounds__(256) void k_wtr(
    const float* __restrict__ hm1_w, const float* __restrict__ hv1_w,
    const float* __restrict__ hm1_b, const float* __restrict__ hv1_b,
    u16* __restrict__ Wt, float* __restrict__ biasF)
{
  int i = blockIdx.x * 256 + threadIdx.x;   // < 9*256*256
  int ci = i & 255, co = (i >> 8) & 255, tap = i >> 16;
  float v = (co < CH_) ? hm1_w[((size_t)co * C_ + ci) * 9 + tap]
                       : hv1_w[((size_t)(co - CH_) * C_ + ci) * 9 + tap];
  Wt[i] = f2bf(v);
  if (i < CH_) biasF[i] = hm1_b[i];
  else if (i < 2 * CH_) biasF[i] = hv1_b[i - CH_];
}

// ---------- fused 3x3 conv (both heads) as implicit GEMM: C[co][px'] ----------
__global__ __launch_bounds__(256) void k_conv3m(
    const u16* __restrict__ inTp, const u16* __restrict__ Wt,
    const float* __restrict__ biasF, float* __restrict__ mp0, float* __restrict__ mp1)
{
  int px0 = blockIdx.x << 7;           // 0..32 (33 tiles of 128 px')
  int cot = blockIdx.y;                // 0..1 (co halves of 256 fused)
  int b = blockIdx.z >> 1, ks = blockIdx.z & 1;
  int t = threadIdx.x, lane = t & 63, w = t >> 6;
  int wr = w >> 1, wc = w & 1;
  __shared__ __align__(16) u16 Al[128 * 64];   // weights: 128 co rows x 64 ci
  __shared__ __align__(16) u16 Bl[128 * 64];   // input:   128 px rows x 64 ci
  f32x4 zero = {0.f, 0.f, 0.f, 0.f};
  f32x4 acc[4][4];
  #pragma unroll
  for (int i = 0; i < 4; i++){
    #pragma unroll
    for (int j = 0; j < 4; j++) acc[i][j] = zero;
  }
  const u16* inb = inTp + ((size_t)b * PXTOT + PXPAD + px0) * C_;
  for (int s = ks * 18; s < ks * 18 + 18; s++){
    int tap = s >> 2, cic = (s & 3) << 6;
    int ky = tap / 3, kx = tap - ky * 3;
    int off = (ky - 1) * 66 + (kx - 1);
    stage_tile(Wt + ((size_t)tap * 256 + cot * 128) * C_ + cic, C_, Al, t);
    stage_tile(inb + (ptrdiff_t)off * C_ + cic, C_, Bl, t);
    __syncthreads();
    #pragma unroll
    for (int kh = 0; kh < 2; kh++){
      short8 af[4], bfv[4];
      #pragma unroll
      for (int i = 0; i < 4; i++){
        af[i]  = frag_ld(Al, wr * 64 + i * 16 + (lane & 15), kh * 4 + (lane >> 4));
        bfv[i] = frag_ld(Bl, wc * 64 + i * 16 + (lane & 15), kh * 4 + (lane >> 4));
      }
      #pragma unroll
      for (int i = 0; i < 4; i++){
        #pragma unroll
        for (int j = 0; j < 4; j++)
          acc[i][j] = MFMA_BF16(af[i], bfv[j], acc[i][j]);
      }
    }
    __syncthreads();
  }
  float* P = ks ? mp1 : mp0;
  #pragma unroll
  for (int i = 0; i < 4; i++){
    #pragma unroll
    for (int j = 0; j < 4; j++){
      int pxp = px0 + wc * 64 + j * 16 + (lane & 15);
      int y = pxp / 66;
      int xm = pxp - y * 66;
      bool valid = (xm >= 1 && xm <= 64);
      int outn = y * 64 + xm - 1;
      #pragma unroll
      for (int r = 0; r < 4; r++){
        int co = cot * 128 + wr * 64 + i * 16 + (lane >> 4) * 4 + r;
        if (valid){
          float bco = ks ? 0.f : biasF[co];
          P[((size_t)(b * 256 + co)) * N_ + outn] = acc[i][j][r] + bco;
        }
      }
    }
  }
}

// ---------- batchnorm stats over (B,H,W) per fused channel (sums 2 K-parts) ----------
__global__ __launch_bounds__(256) void k_bnstats2(
    const float* __restrict__ p0, const float* __restrict__ p1, float* __restrict__ stats)
{
  int ch = blockIdx.x, t = threadIdx.x;   // ch in [0,256)
  __shared__ float r1[256], r2[256];
  float s1 = 0.f, s2 = 0.f;
  for (int i = t; i < B_ * N_; i += 256){
    int b = i >> 12, n = i & (N_ - 1);
    size_t idx = ((size_t)(b * 256 + ch)) * N_ + n;
    float v = p0[idx] + p1[idx];
    s1 += v; s2 += v * v;
  }
  r1[t] = s1; r2[t] = s2; __syncthreads();
  for (int o = 128; o > 0; o >>= 1){
    if (t < o){ r1[t] += r1[t + o]; r2[t] += r2[t + o]; }
    __syncthreads();
  }
  if (t == 0){
    float mean = r1[0] / (float)(B_ * N_);
    float var = r2[0] / (float)(B_ * N_) - mean * mean;
    stats[ch * 2] = mean;
    stats[ch * 2 + 1] = rsqrtf(var + 1e-5f);
  }
}

// ---------- relu(bn(mid)) -> 1x1 conv to 2 channels (per head, choff) ----------
__global__ __launch_bounds__(256) void k_head2(
    const float* __restrict__ p0, const float* __restrict__ p1,
    const float* __restrict__ stats,
    const float* __restrict__ g, const float* __restrict__ bb,
    const float* __restrict__ w2, const float* __restrict__ b2,
    float* __restrict__ outp, int choff)
{
  int idx = blockIdx.x * 256 + threadIdx.x;
  int b = idx >> 12, n = idx & (N_ - 1);
  float a0 = 0.f, a1 = 0.f;
  for (int ch = 0; ch < CH_; ch++){
    int fc = choff + ch;
    size_t id = ((size_t)(b * 256 + fc)) * N_ + n;
    float v = p0[id] + p1[id];
    float rr = (v - stats[fc * 2]) * stats[fc * 2 + 1] * g[ch] + bb[ch];
    rr = fmaxf(rr, 0.f);
    a0 += w2[ch] * rr;
    a1 += w2[CH_ + ch] * rr;
  }
  outp[(size_t)(b * 2) * N_ + n] = a0 + b2[0];
  outp[(size_t)(b * 2 + 1) * N_ + n] = a1 + b2[1];
}

extern "C" void kernel_launch(void* const* d_in, const int* in_sizes, int n_in,
                              void* d_out, int out_size, void* d_ws, size_t ws_size,
                              hipStream_t stream)
{
  const float* img   = (const float*)d_in[0];
  const float* txt   = (const float*)d_in[1];
  const float* dens  = (const float*)d_in[2];
  const float* tp_w  = (const float*)d_in[3];
  const float* tp_b  = (const float*)d_in[4];
  const float* wv    = (const float*)d_in[9];
  const float* bv    = (const float*)d_in[10];
  const float* wo    = (const float*)d_in[11];
  const float* bo    = (const float*)d_in[12];
  const float* ln_g  = (const float*)d_in[13];
  const float* ln_b  = (const float*)d_in[14];
  const float* op_w  = (const float*)d_in[15];
  const float* op_b  = (const float*)d_in[16];
  const float* hm1_w = (const float*)d_in[17];
  const float* hm1_b = (const float*)d_in[18];
  const float* hm_g  = (const float*)d_in[19];
  const float* hm_b  = (const float*)d_in[20];
  const float* hm2_w = (const float*)d_in[21];
  const float* hm2_b = (const float*)d_in[22];
  const float* hv1_w = (const float*)d_in[23];
  const float* hv1_b = (const float*)d_in[24];
  const float* hv_g  = (const float*)d_in[25];
  const float* hv_b  = (const float*)d_in[26];
  const float* hv2_w = (const float*)d_in[27];
  const float* hv2_b = (const float*)d_in[28];
  const float* temp  = (const float*)d_in[29];

  char* wsb = (char*)d_ws;
  size_t off = 0;
  auto alloc = [&](size_t bytes) -> void* {
    void* p = wsb + off;
    off += (bytes + 255) & ~(size_t)255;
    return p;
  };
  u16*   Km     = (u16*)  alloc((size_t)B_ * N_ * N_ * sizeof(u16));   // 67.1 MB
  u16*   snb16  = (u16*)  alloc((size_t)B_ * N_ * C_ * sizeof(u16));   // 4.19 MB
  u16*   srcT16 = (u16*)  alloc((size_t)B_ * C_ * N_ * sizeof(u16));   // 4.19 MB
  u16*   usrcT  = (u16*)  alloc((size_t)B_ * C_ * N_ * sizeof(u16));   // 4.19 MB
  float* part1  = (float*)alloc((size_t)B_ * N_ * C_ * sizeof(float)); // 8.39 MB
  u16*   inTp   = (u16*)  alloc((size_t)B_ * PXTOT * C_ * sizeof(u16));// 4.52 MB
  u16*   Wt     = (u16*)  alloc((size_t)9 * 256 * C_ * sizeof(u16));   // 1.18 MB
  float* biasF  = (float*)alloc(256 * sizeof(float));
  float* txt_emb= (float*)alloc(B_ * C_ * sizeof(float));
  float* attn_c = (float*)alloc(B_ * C_ * sizeof(float));
  float* txt_n  = (float*)alloc(B_ * C_ * sizeof(float));
  float* cosv   = (float*)alloc(B_ * N_ * sizeof(float));
  float* qm     = (float*)alloc(B_ * N_ * sizeof(float));
  float* pm     = (float*)alloc(B_ * N_ * sizeof(float));
  float* uu     = (float*)alloc(B_ * N_ * sizeof(float));
  float* vvv    = (float*)alloc(B_ * N_ * sizeof(float));
  float* colsum = (float*)alloc(B_ * N_ * sizeof(float));
  float* stats  = (float*)alloc(256 * 2 * sizeof(float));

  // aliases (disjoint lifetimes):
  // part0/midp0 over (snb16 + srcT16) = exactly 8.39 MB; midp1 over part1.
  float* part0 = (float*)snb16;
  float* midp0 = part0;
  float* midp1 = part1;

  float* outf  = (float*)d_out;
  float* outhm = outf + (size_t)B_ * C_ * N_;
  float* outhv = outhm + (size_t)B_ * 2 * N_;

  k_text<<<B_, 256, 0, stream>>>(txt, tp_w, tp_b, wv, bv, wo, bo, txt_emb, attn_c, txt_n);
  k_source<<<dim3(N_ / TN, B_), 256, 0, stream>>>(img, attn_c, ln_g, ln_b, txt_n, srcT16, snb16, cosv);
  k_qmarg<<<B_, 256, 0, stream>>>(dens, qm);
  k_pmarg<<<B_, 256, 0, stream>>>(cosv, temp, pm);
  k_zero<<<(B_ * N_ + 255) / 256, 256, 0, stream>>>(colsum, B_ * N_);
  // conv prep with no deps on GEMM chain: weight transpose + zero padded input buffer
  k_wtr<<<9 * 256, 256, 0, stream>>>(hm1_w, hv1_w, hm1_b, hv1_b, Wt, biasF);
  k_zero<<<((int)((size_t)B_ * PXTOT * C_ / 2) + 255) / 256, 256, 0, stream>>>((float*)inTp, (int)((size_t)B_ * PXTOT * C_ / 2));
  k_kgen<<<dim3(N_ / 128, N_ / 128, B_), 256, 0, stream>>>(snb16, Km, colsum);
  // Sinkhorn (K symmetric: K^T x == K x)
  k_div<<<(B_ * N_ + 255) / 256, 256, 0, stream>>>(qm, colsum, vvv);        // vv1
  k_mv<<<B_ * N_ / 4, 256, 0, stream>>>(Km, vvv, pm, uu);                   // u1
  k_mv<<<B_ * N_ / 4, 256, 0, stream>>>(Km, uu, qm, vvv);                   // vv2
  k_mv<<<B_ * N_ / 4, 256, 0, stream>>>(Km, vvv, pm, uu);                   // u2
  k_mv<<<B_ * N_ / 4, 256, 0, stream>>>(Km, uu, qm, vvv);                   // vv3
  k_mv<<<B_ * N_ / 4, 256, 0, stream>>>(Km, vvv, pm, uu);                   // u3
  k_uscale<<<(B_ * C_ * N_ / 8 + 255) / 256, 256, 0, stream>>>(srcT16, uu, usrcT);
  k_full<<<dim3(N_ / 128, C_ / 128, B_ * KSPLIT), 256, 0, stream>>>(Km, usrcT, part0, part1);
  k_opconv<<<dim3(N_ / GT, C_ / GT, B_), 256, 0, stream>>>(op_w, op_b, part0, part1, vvv, img, outf);
  // fused heads: transpose -> implicit-GEMM conv (both heads) -> BN stats -> heads
  k_tr<<<dim3(N_ / 64, 4, B_), 256, 0, stream>>>(outf, inTp);
  k_conv3m<<<dim3(33, 2, B_ * KSPLIT), 256, 0, stream>>>(inTp, Wt, biasF, midp0, midp1);
  k_bnstats2<<<256, 256, 0, stream>>>(midp0, midp1, stats);
  k_head2<<<B_ * N_ / 256, 256, 0, stream>>>(midp0, midp1, stats, hm_g, hm_b, hm2_w, hm2_b, outhm, 0);
  k_head2<<<B_ * N_ / 256, 256, 0, stream>>>(midp0, midp1, stats, hv_g, hv_b, hv2_w, hv2_b, outhv, CH_);
}